// Round 8
// baseline (454.495 us; speedup 1.0000x reference)
//
#include <hip/hip_runtime.h>
#include <math.h>

#define IN_CH   128
#define HID     128
#define OUT_CH  64
#define NGRAPH  512

// ---------------- CSR build ----------------

__global__ __launch_bounds__(256) void cnt_init_k(int* cnt, int n) {
    int i = blockIdx.x * 256 + threadIdx.x;
    if (i < n) cnt[i] = 0;
}

__global__ __launch_bounds__(256) void count_k(const int* __restrict__ ei, int* cnt, int E) {
    int e = blockIdx.x * 256 + threadIdx.x;
    if (e < E) atomicAdd(&cnt[ei[E + e]], 1);     // in-degree of dst (edges only)
}

// partials reduction + dinv fused (both read cnt)
__global__ __launch_bounds__(256) void scan_part_k(const int* __restrict__ cnt,
                                                   int* __restrict__ bsum,
                                                   float* __restrict__ dinv, int n) {
    __shared__ int red[256];
    int i = blockIdx.x * 256 + threadIdx.x;
    int v = (i < n) ? cnt[i] : 0;
    if (i < n) dinv[i] = rsqrtf((float)v + 1.0f);   // +1 self loop
    red[threadIdx.x] = v;
    __syncthreads();
    for (int off = 128; off > 0; off >>= 1) {
        if (threadIdx.x < off) red[threadIdx.x] += red[threadIdx.x + off];
        __syncthreads();
    }
    if (threadIdx.x == 0) bsum[blockIdx.x] = red[0];
}

// single block; nb <= 256 (N <= 65536)
__global__ __launch_bounds__(256) void scan_top_k(const int* __restrict__ bsum,
                                                  int* __restrict__ boff, int nb) {
    __shared__ int sh[256];
    int t = threadIdx.x;
    int v = (t < nb) ? bsum[t] : 0;
    sh[t] = v;
    __syncthreads();
    for (int off = 1; off < 256; off <<= 1) {
        int u = (t >= off) ? sh[t - off] : 0;
        __syncthreads();
        sh[t] += u;
        __syncthreads();
    }
    if (t < nb) boff[t] = sh[t] - v;              // exclusive
}

__global__ __launch_bounds__(256) void scan_down_k(const int* __restrict__ cnt,
                                                   const int* __restrict__ boff,
                                                   int* __restrict__ rowptr,
                                                   int* __restrict__ cursor, int n) {
    __shared__ int sh[256];
    int i = blockIdx.x * 256 + threadIdx.x;
    int t = threadIdx.x;
    int v = (i < n) ? cnt[i] : 0;
    sh[t] = v;
    __syncthreads();
    for (int off = 1; off < 256; off <<= 1) {
        int u = (t >= off) ? sh[t - off] : 0;
        __syncthreads();
        sh[t] += u;
        __syncthreads();
    }
    if (i < n) {
        int o = boff[blockIdx.x] + sh[t] - v;     // exclusive prefix
        rowptr[i] = o; cursor[i] = o;
        if (i == n - 1) rowptr[n] = o + v;        // == E
    }
}

// bucket edges by dst: esrc[pos] = src   (norm recomputed in gather)
__global__ __launch_bounds__(256) void scatter_k(const int* __restrict__ ei,
                                                 int* cursor, int* __restrict__ esrc, int E) {
    int e = blockIdx.x * 256 + threadIdx.x;
    if (e >= E) return;
    int s = ei[e], d = ei[E + e];
    int pos = atomicAdd(&cursor[d], 1);
    esrc[pos] = s;
}

// ---------------- GEMM: C[nRows x COLS] = A[nRows x 128] @ W[128 x COLS] (+bias) ----------------
// 64 rows/block, 256 threads, K in 4 chunks of 32 (LDS ~24.8 KB -> 6 blocks/CU).
// Thread (tr,tc) owns rows tr*4..+3, cols {g*64 + tc*4}. ws b128 read: 16 lanes cover
// 64 consecutive floats -> 2 lanes/bank -> conflict-free.

template<int COLS, bool BIAS>
__global__ __launch_bounds__(256) void gemm_k(const float* __restrict__ A,
                                              const float* __restrict__ W,
                                              const float* __restrict__ bias,
                                              float* __restrict__ C, int nRows) {
    constexpr int NG = COLS / 64;                 // groups of 64 cols (2 or 1)
    __shared__ float ws[32 * COLS];               // K-chunk x COLS
    __shared__ float xs[64 * 33];                 // rows x K-chunk (padded)
    const int tid = threadIdx.x;
    const int rowBase = blockIdx.x * 64;
    const int tr = tid >> 4;                      // rows tr*4..tr*4+3
    const int tc = tid & 15;                      // cols g*64 + tc*4

    float acc[4][NG][4];
#pragma unroll
    for (int i = 0; i < 4; ++i)
#pragma unroll
        for (int g = 0; g < NG; ++g)
#pragma unroll
            for (int j = 0; j < 4; ++j) acc[i][g][j] = 0.0f;

    for (int kc = 0; kc < 4; ++kc) {
        for (int i = tid; i < 32 * COLS / 4; i += 256) {
            int r = i / (COLS / 4), c = (i % (COLS / 4)) * 4;
            *(float4*)&ws[r * COLS + c] = *(const float4*)&W[(kc * 32 + r) * COLS + c];
        }
        for (int i = tid; i < 64 * 8; i += 256) {  // 64 rows x 32 k = 512 float4
            int r = i >> 3, c = (i & 7) * 4;
            float4 v = make_float4(0.f, 0.f, 0.f, 0.f);
            if (rowBase + r < nRows)
                v = *(const float4*)&A[(size_t)(rowBase + r) * 128 + kc * 32 + c];
            xs[r * 33 + c + 0] = v.x; xs[r * 33 + c + 1] = v.y;
            xs[r * 33 + c + 2] = v.z; xs[r * 33 + c + 3] = v.w;
        }
        __syncthreads();
#pragma unroll 4
        for (int k = 0; k < 32; ++k) {
            float xv[4];
#pragma unroll
            for (int i = 0; i < 4; ++i) xv[i] = xs[(tr * 4 + i) * 33 + k];
            float wv[NG][4];
#pragma unroll
            for (int g = 0; g < NG; ++g)
                *(float4*)&wv[g][0] = *(const float4*)&ws[k * COLS + g * 64 + tc * 4];
#pragma unroll
            for (int i = 0; i < 4; ++i)
#pragma unroll
                for (int g = 0; g < NG; ++g)
#pragma unroll
                    for (int j = 0; j < 4; ++j)
                        acc[i][g][j] = fmaf(xv[i], wv[g][j], acc[i][g][j]);
        }
        __syncthreads();
    }

#pragma unroll
    for (int i = 0; i < 4; ++i) {
        int row = rowBase + tr * 4 + i;
        if (row < nRows) {
#pragma unroll
            for (int g = 0; g < NG; ++g) {
                float4 v = *(float4*)&acc[i][g][0];
                if (BIAS) {
                    float4 bv = *(const float4*)&bias[g * 64 + tc * 4];
                    v.x += bv.x; v.y += bv.y; v.z += bv.z; v.w += bv.w;
                }
                *(float4*)&C[(size_t)row * COLS + g * 64 + tc * 4] = v;
            }
        }
    }
}

// ---------------- fused gather-aggregate + self-loop + bias + relu ----------------
// 16 lanes per dst node; each lane owns channels c..c+3 and c+64..c+67 (2 float4
// gathers per edge -> 16 outstanding dwordx4 per wave at 8-deep). Predicated
// (no tail loop). norm computed from dinv (L2-resident).

__global__ __launch_bounds__(256) void gather_k(const int* __restrict__ rowptr,
                                                const int* __restrict__ esrc,
                                                const float* __restrict__ dinv,
                                                const float* __restrict__ h,
                                                const float* __restrict__ bias,
                                                float* __restrict__ out, int n) {
    int node = blockIdx.x * 16 + (threadIdx.x >> 4);
    if (node >= n) return;
    int c = (threadIdx.x & 15) * 4;
    float dd = dinv[node];
    float s2 = dd * dd;
    float4 a0 = *(const float4*)&h[(size_t)node * HID + c];        // self loop
    float4 a1 = *(const float4*)&h[(size_t)node * HID + c + 64];
    a0.x *= s2; a0.y *= s2; a0.z *= s2; a0.w *= s2;
    a1.x *= s2; a1.y *= s2; a1.z *= s2; a1.w *= s2;

    int j = rowptr[node], end = rowptr[node + 1];
    for (; j < end; j += 8) {
        float w[8];
        float4 h0[8], h1[8];
#pragma unroll
        for (int u = 0; u < 8; ++u) {
            bool ok = (j + u) < end;
            int su = ok ? esrc[j + u] : node;          // safe addr when past end
            w[u] = ok ? dinv[su] * dd : 0.0f;
            const float* row = &h[(size_t)su * HID + c];
            h0[u] = *(const float4*)row;
            h1[u] = *(const float4*)(row + 64);
        }
#pragma unroll
        for (int u = 0; u < 8; ++u) {
            a0.x = fmaf(h0[u].x, w[u], a0.x); a0.y = fmaf(h0[u].y, w[u], a0.y);
            a0.z = fmaf(h0[u].z, w[u], a0.z); a0.w = fmaf(h0[u].w, w[u], a0.w);
            a1.x = fmaf(h1[u].x, w[u], a1.x); a1.y = fmaf(h1[u].y, w[u], a1.y);
            a1.z = fmaf(h1[u].z, w[u], a1.z); a1.w = fmaf(h1[u].w, w[u], a1.w);
        }
    }

    float4 b0 = *(const float4*)&bias[c];
    float4 b1 = *(const float4*)&bias[c + 64];
    a0.x = fmaxf(a0.x + b0.x, 0.f); a0.y = fmaxf(a0.y + b0.y, 0.f);
    a0.z = fmaxf(a0.z + b0.z, 0.f); a0.w = fmaxf(a0.w + b0.w, 0.f);
    a1.x = fmaxf(a1.x + b1.x, 0.f); a1.y = fmaxf(a1.y + b1.y, 0.f);
    a1.z = fmaxf(a1.z + b1.z, 0.f); a1.w = fmaxf(a1.w + b1.w, 0.f);
    float* orow = &out[(size_t)node * HID + c];
    *(float4*)orow = a0;
    *(float4*)(orow + 64) = a1;
}

// ---------------- global mean pool (batch sorted) ----------------

__global__ __launch_bounds__(128) void pool_k(const int* __restrict__ batch,
                                              const float* __restrict__ h,
                                              float* __restrict__ pooled, int n) {
    int g = blockIdx.x;
    __shared__ int sh[2];
    if (threadIdx.x < 2) {
        int target = g + (int)threadIdx.x;
        int lo = 0, hi = n;
        while (lo < hi) {
            int mid = (lo + hi) >> 1;
            if (batch[mid] < target) lo = mid + 1; else hi = mid;
        }
        sh[threadIdx.x] = lo;
    }
    __syncthreads();
    int lo = sh[0], hi = sh[1];
    float sum = 0.f;
    for (int i = lo; i < hi; ++i) sum += h[(size_t)i * HID + threadIdx.x];
    float cnt = (float)(hi - lo);
    pooled[(size_t)g * HID + threadIdx.x] = sum / fmaxf(cnt, 1.0f);
}

// ---------------- launch ----------------

extern "C" void kernel_launch(void* const* d_in, const int* in_sizes, int n_in,
                              void* d_out, int out_size, void* d_ws, size_t ws_size,
                              hipStream_t stream) {
    const float* x     = (const float*)d_in[0];
    const int*   ei    = (const int*)d_in[1];
    const int*   batch = (const int*)d_in[2];
    const float* W1    = (const float*)d_in[3];
    const float* b1    = (const float*)d_in[4];
    const float* W2    = (const float*)d_in[5];
    const float* b2    = (const float*)d_in[6];
    const float* Wl    = (const float*)d_in[7];
    const float* bl    = (const float*)d_in[8];

    const int N = in_sizes[0] / IN_CH;
    const int E = in_sizes[1] / 2;

    float* out    = (float*)d_out;
    float* pooled = out + (size_t)N * OUT_CH;

    // ws layout: dinv[N] | cnt[N] | rowptr[N+1] | cursor[N] | bsum[256] | boff[256]
    //            | esrc[E int] | bufA[N*128] | bufB[N*128]
    char* w = (char*)d_ws;
    auto align16 = [](size_t s) { return (s + 15) & ~(size_t)15; };
    float* dinv   = (float*)w;                 w += align16((size_t)N * 4);
    int*   cnt    = (int*)w;                   w += align16((size_t)N * 4);
    int*   rowptr = (int*)w;                   w += align16((size_t)(N + 1) * 4);
    int*   cursor = (int*)w;                   w += align16((size_t)N * 4);
    int*   bsum   = (int*)w;                   w += align16(256 * 4);
    int*   boff   = (int*)w;                   w += align16(256 * 4);
    int*   esrc   = (int*)w;                   w += align16((size_t)E * 4);
    float* bufA   = (float*)w;                 w += align16((size_t)N * HID * 4);
    float* bufB   = (float*)w;

    const int nbN = (N + 255) / 256;           // 196 for N=50000 (<=256 for scan_top)
    const int nbE = (E + 255) / 256;
    const int nbG = (N + 15) / 16;             // gather: 16 nodes per block
    const int gb  = (N + 63) / 64;             // gemm blocks

    // CSR build (once, reused by both convs)
    cnt_init_k <<<nbN, 256, 0, stream>>>(cnt, N);
    count_k    <<<nbE, 256, 0, stream>>>(ei, cnt, E);
    scan_part_k<<<nbN, 256, 0, stream>>>(cnt, bsum, dinv, N);
    scan_top_k <<<1,   256, 0, stream>>>(bsum, boff, nbN);
    scan_down_k<<<nbN, 256, 0, stream>>>(cnt, boff, rowptr, cursor, N);
    scatter_k  <<<nbE, 256, 0, stream>>>(ei, cursor, esrc, E);

    // conv1
    gemm_k<HID, false><<<gb, 256, 0, stream>>>(x, W1, nullptr, bufA, N);
    gather_k<<<nbG, 256, 0, stream>>>(rowptr, esrc, dinv, bufA, b1, bufB, N);

    // conv2
    gemm_k<HID, false><<<gb, 256, 0, stream>>>(bufB, W2, nullptr, bufA, N);
    gather_k<<<nbG, 256, 0, stream>>>(rowptr, esrc, dinv, bufA, b2, bufB, N);

    // head
    gemm_k<OUT_CH, true><<<gb, 256, 0, stream>>>(bufB, Wl, bl, out, N);
    pool_k<<<NGRAPH, 128, 0, stream>>>(batch, bufB, pooled, N);
}

// Round 13
// 429.059 us; speedup vs baseline: 1.0593x; 1.0593x over previous
//
#include <hip/hip_runtime.h>
#include <math.h>

#define IN_CH   128
#define HID     128
#define OUT_CH  64
#define NGRAPH  512

// ---------------- CSR build ----------------

__global__ __launch_bounds__(256) void cnt_init_k(int* cnt, int n) {
    int i = blockIdx.x * 256 + threadIdx.x;
    if (i < n) cnt[i] = 0;
}

__global__ __launch_bounds__(256) void count_k(const int* __restrict__ ei, int* cnt, int E) {
    int e = blockIdx.x * 256 + threadIdx.x;
    if (e < E) atomicAdd(&cnt[ei[E + e]], 1);     // in-degree of dst (edges only)
}

// partials reduction + dinv fused (both read cnt)
__global__ __launch_bounds__(256) void scan_part_k(const int* __restrict__ cnt,
                                                   int* __restrict__ bsum,
                                                   float* __restrict__ dinv, int n) {
    __shared__ int red[256];
    int i = blockIdx.x * 256 + threadIdx.x;
    int v = (i < n) ? cnt[i] : 0;
    if (i < n) dinv[i] = rsqrtf((float)v + 1.0f);   // +1 self loop
    red[threadIdx.x] = v;
    __syncthreads();
    for (int off = 128; off > 0; off >>= 1) {
        if (threadIdx.x < off) red[threadIdx.x] += red[threadIdx.x + off];
        __syncthreads();
    }
    if (threadIdx.x == 0) bsum[blockIdx.x] = red[0];
}

// single block; nb <= 256 (N <= 65536)
__global__ __launch_bounds__(256) void scan_top_k(const int* __restrict__ bsum,
                                                  int* __restrict__ boff, int nb) {
    __shared__ int sh[256];
    int t = threadIdx.x;
    int v = (t < nb) ? bsum[t] : 0;
    sh[t] = v;
    __syncthreads();
    for (int off = 1; off < 256; off <<= 1) {
        int u = (t >= off) ? sh[t - off] : 0;
        __syncthreads();
        sh[t] += u;
        __syncthreads();
    }
    if (t < nb) boff[t] = sh[t] - v;              // exclusive
}

__global__ __launch_bounds__(256) void scan_down_k(const int* __restrict__ cnt,
                                                   const int* __restrict__ boff,
                                                   int* __restrict__ rowptr,
                                                   int* __restrict__ cursor, int n) {
    __shared__ int sh[256];
    int i = blockIdx.x * 256 + threadIdx.x;
    int t = threadIdx.x;
    int v = (i < n) ? cnt[i] : 0;
    sh[t] = v;
    __syncthreads();
    for (int off = 1; off < 256; off <<= 1) {
        int u = (t >= off) ? sh[t - off] : 0;
        __syncthreads();
        sh[t] += u;
        __syncthreads();
    }
    if (i < n) {
        int o = boff[blockIdx.x] + sh[t] - v;     // exclusive prefix
        rowptr[i] = o; cursor[i] = o;
        if (i == n - 1) rowptr[n] = o + v;        // == E
    }
}

// bucket edges by dst: ebuf[pos] = (src, norm)  -- norm precomputed, arrives with index
__global__ __launch_bounds__(256) void scatter_k(const int* __restrict__ ei,
                                                 const float* __restrict__ dinv,
                                                 int* cursor, int2* __restrict__ ebuf, int E) {
    int e = blockIdx.x * 256 + threadIdx.x;
    if (e >= E) return;
    int s = ei[e], d = ei[E + e];
    int pos = atomicAdd(&cursor[d], 1);
    ebuf[pos] = make_int2(s, __float_as_int(dinv[s] * dinv[d]));
}

// ---------------- GEMM: C[nRows x COLS] = A[nRows x 128] @ W[128 x COLS] (+bias) ----------------
// 64 rows/block, 256 threads, K in 4 chunks of 32 (LDS ~24.8 KB). Thread (tr,tc) owns
// rows tr*4..+3, cols {g*64 + tc*4}. ws b128 read: 16 lanes cover 64 consecutive
// floats -> 2 lanes/bank -> conflict-free.

template<int COLS, bool BIAS>
__global__ __launch_bounds__(256) void gemm_k(const float* __restrict__ A,
                                              const float* __restrict__ W,
                                              const float* __restrict__ bias,
                                              float* __restrict__ C, int nRows) {
    constexpr int NG = COLS / 64;                 // groups of 64 cols (2 or 1)
    __shared__ float ws[32 * COLS];               // K-chunk x COLS
    __shared__ float xs[64 * 33];                 // rows x K-chunk (padded)
    const int tid = threadIdx.x;
    const int rowBase = blockIdx.x * 64;
    const int tr = tid >> 4;                      // rows tr*4..tr*4+3
    const int tc = tid & 15;                      // cols g*64 + tc*4

    float acc[4][NG][4];
#pragma unroll
    for (int i = 0; i < 4; ++i)
#pragma unroll
        for (int g = 0; g < NG; ++g)
#pragma unroll
            for (int j = 0; j < 4; ++j) acc[i][g][j] = 0.0f;

    for (int kc = 0; kc < 4; ++kc) {
        for (int i = tid; i < 32 * COLS / 4; i += 256) {
            int r = i / (COLS / 4), c = (i % (COLS / 4)) * 4;
            *(float4*)&ws[r * COLS + c] = *(const float4*)&W[(kc * 32 + r) * COLS + c];
        }
        for (int i = tid; i < 64 * 8; i += 256) {  // 64 rows x 32 k = 512 float4
            int r = i >> 3, c = (i & 7) * 4;
            float4 v = make_float4(0.f, 0.f, 0.f, 0.f);
            if (rowBase + r < nRows)
                v = *(const float4*)&A[(size_t)(rowBase + r) * 128 + kc * 32 + c];
            xs[r * 33 + c + 0] = v.x; xs[r * 33 + c + 1] = v.y;
            xs[r * 33 + c + 2] = v.z; xs[r * 33 + c + 3] = v.w;
        }
        __syncthreads();
#pragma unroll 4
        for (int k = 0; k < 32; ++k) {
            float xv[4];
#pragma unroll
            for (int i = 0; i < 4; ++i) xv[i] = xs[(tr * 4 + i) * 33 + k];
            float wv[NG][4];
#pragma unroll
            for (int g = 0; g < NG; ++g)
                *(float4*)&wv[g][0] = *(const float4*)&ws[k * COLS + g * 64 + tc * 4];
#pragma unroll
            for (int i = 0; i < 4; ++i)
#pragma unroll
                for (int g = 0; g < NG; ++g)
#pragma unroll
                    for (int j = 0; j < 4; ++j)
                        acc[i][g][j] = fmaf(xv[i], wv[g][j], acc[i][g][j]);
        }
        __syncthreads();
    }

#pragma unroll
    for (int i = 0; i < 4; ++i) {
        int row = rowBase + tr * 4 + i;
        if (row < nRows) {
#pragma unroll
            for (int g = 0; g < NG; ++g) {
                float4 v = *(float4*)&acc[i][g][0];
                if (BIAS) {
                    float4 bv = *(const float4*)&bias[g * 64 + tc * 4];
                    v.x += bv.x; v.y += bv.y; v.z += bv.z; v.w += bv.w;
                }
                *(float4*)&C[(size_t)row * COLS + g * 64 + tc * 4] = v;
            }
        }
    }
}

// ---------------- gather variant A: edge-prefetch pipeline (under test) ----------------
// 32 lanes/node, float4/lane, 8-edge batches; batch k+1's int2s are loaded during
// batch k's gathers/FMAs. Invalid slots: weight=0, address=h[node] (cache hit).

__global__ __launch_bounds__(256) void gather_pf_k(const int* __restrict__ rowptr,
                                                   const int2* __restrict__ ebuf,
                                                   const float* __restrict__ dinv,
                                                   const float* __restrict__ h,
                                                   const float* __restrict__ bias,
                                                   float* __restrict__ out, int n) {
    int node = blockIdx.x * 8 + (threadIdx.x >> 5);
    if (node >= n) return;
    int c = (threadIdx.x & 31) * 4;
    float dd = dinv[node];
    float s2 = dd * dd;
    float4 acc = *(const float4*)&h[(size_t)node * HID + c];   // self loop
    acc.x *= s2; acc.y *= s2; acc.z *= s2; acc.w *= s2;

    int j = rowptr[node], end = rowptr[node + 1];
    int2 e[8];
#pragma unroll
    for (int u = 0; u < 8; ++u)
        e[u] = (j + u < end) ? ebuf[j + u] : make_int2(node, 0);

    while (j < end) {
        float4 hv[8];
#pragma unroll
        for (int u = 0; u < 8; ++u)
            hv[u] = *(const float4*)&h[(size_t)e[u].x * HID + c];

        int jn = j + 8;
        int2 en[8];
#pragma unroll
        for (int u = 0; u < 8; ++u)
            en[u] = (jn + u < end) ? ebuf[jn + u] : make_int2(node, 0);

#pragma unroll
        for (int u = 0; u < 8; ++u) {
            float w0 = __int_as_float(e[u].y);
            acc.x = fmaf(hv[u].x, w0, acc.x); acc.y = fmaf(hv[u].y, w0, acc.y);
            acc.z = fmaf(hv[u].z, w0, acc.z); acc.w = fmaf(hv[u].w, w0, acc.w);
        }
#pragma unroll
        for (int u = 0; u < 8; ++u) e[u] = en[u];
        j = jn;
    }

    float4 bv = *(const float4*)&bias[c];
    acc.x = fmaxf(acc.x + bv.x, 0.f);
    acc.y = fmaxf(acc.y + bv.y, 0.f);
    acc.z = fmaxf(acc.z + bv.z, 0.f);
    acc.w = fmaxf(acc.w + bv.w, 0.f);
    *(float4*)&out[(size_t)node * HID + c] = acc;
}

// ---------------- gather variant B: R4 control (measured 69.5 us) ----------------
// 32 lanes/node, float4/lane, 8-edge-deep unroll + tail; no prefetch pipeline.

__global__ __launch_bounds__(256) void gather_r4_k(const int* __restrict__ rowptr,
                                                   const int2* __restrict__ ebuf,
                                                   const float* __restrict__ dinv,
                                                   const float* __restrict__ h,
                                                   const float* __restrict__ bias,
                                                   float* __restrict__ out, int n) {
    int node = blockIdx.x * 8 + (threadIdx.x >> 5);
    if (node >= n) return;
    int c = (threadIdx.x & 31) * 4;
    float d = dinv[node];
    float s2 = d * d;
    float4 acc = *(const float4*)&h[(size_t)node * HID + c];   // self loop
    acc.x *= s2; acc.y *= s2; acc.z *= s2; acc.w *= s2;

    int j = rowptr[node], end = rowptr[node + 1];
    for (; j + 7 < end; j += 8) {
        int2 e[8];
        float4 hv[8];
#pragma unroll
        for (int u = 0; u < 8; ++u) e[u] = ebuf[j + u];
#pragma unroll
        for (int u = 0; u < 8; ++u)
            hv[u] = *(const float4*)&h[(size_t)e[u].x * HID + c];
#pragma unroll
        for (int u = 0; u < 8; ++u) {
            float w0 = __int_as_float(e[u].y);
            acc.x = fmaf(hv[u].x, w0, acc.x); acc.y = fmaf(hv[u].y, w0, acc.y);
            acc.z = fmaf(hv[u].z, w0, acc.z); acc.w = fmaf(hv[u].w, w0, acc.w);
        }
    }
    for (; j < end; ++j) {
        int2 e0 = ebuf[j];
        float4 h0 = *(const float4*)&h[(size_t)e0.x * HID + c];
        float w0 = __int_as_float(e0.y);
        acc.x = fmaf(h0.x, w0, acc.x); acc.y = fmaf(h0.y, w0, acc.y);
        acc.z = fmaf(h0.z, w0, acc.z); acc.w = fmaf(h0.w, w0, acc.w);
    }

    float4 bv = *(const float4*)&bias[c];
    acc.x = fmaxf(acc.x + bv.x, 0.f);
    acc.y = fmaxf(acc.y + bv.y, 0.f);
    acc.z = fmaxf(acc.z + bv.z, 0.f);
    acc.w = fmaxf(acc.w + bv.w, 0.f);
    *(float4*)&out[(size_t)node * HID + c] = acc;
}

// ---------------- global mean pool (batch sorted) ----------------

__global__ __launch_bounds__(128) void pool_k(const int* __restrict__ batch,
                                              const float* __restrict__ h,
                                              float* __restrict__ pooled, int n) {
    int g = blockIdx.x;
    __shared__ int sh[2];
    if (threadIdx.x < 2) {
        int target = g + (int)threadIdx.x;
        int lo = 0, hi = n;
        while (lo < hi) {
            int mid = (lo + hi) >> 1;
            if (batch[mid] < target) lo = mid + 1; else hi = mid;
        }
        sh[threadIdx.x] = lo;
    }
    __syncthreads();
    int lo = sh[0], hi = sh[1];
    float sum = 0.f;
    for (int i = lo; i < hi; ++i) sum += h[(size_t)i * HID + threadIdx.x];
    float cnt = (float)(hi - lo);
    pooled[(size_t)g * HID + threadIdx.x] = sum / fmaxf(cnt, 1.0f);
}

// ---------------- launch ----------------

extern "C" void kernel_launch(void* const* d_in, const int* in_sizes, int n_in,
                              void* d_out, int out_size, void* d_ws, size_t ws_size,
                              hipStream_t stream) {
    const float* x     = (const float*)d_in[0];
    const int*   ei    = (const int*)d_in[1];
    const int*   batch = (const int*)d_in[2];
    const float* W1    = (const float*)d_in[3];
    const float* b1    = (const float*)d_in[4];
    const float* W2    = (const float*)d_in[5];
    const float* b2    = (const float*)d_in[6];
    const float* Wl    = (const float*)d_in[7];
    const float* bl    = (const float*)d_in[8];

    const int N = in_sizes[0] / IN_CH;
    const int E = in_sizes[1] / 2;

    float* out    = (float*)d_out;
    float* pooled = out + (size_t)N * OUT_CH;

    // ws layout: dinv[N] | cnt[N] | rowptr[N+1] | cursor[N] | bsum[256] | boff[256]
    //            | ebuf[E int2] | bufA[N*128] | bufB[N*128]
    char* w = (char*)d_ws;
    auto align16 = [](size_t s) { return (s + 15) & ~(size_t)15; };
    float* dinv   = (float*)w;                 w += align16((size_t)N * 4);
    int*   cnt    = (int*)w;                   w += align16((size_t)N * 4);
    int*   rowptr = (int*)w;                   w += align16((size_t)(N + 1) * 4);
    int*   cursor = (int*)w;                   w += align16((size_t)N * 4);
    int*   bsum   = (int*)w;                   w += align16(256 * 4);
    int*   boff   = (int*)w;                   w += align16(256 * 4);
    int2*  ebuf   = (int2*)w;                  w += align16((size_t)E * 8);
    float* bufA   = (float*)w;                 w += align16((size_t)N * HID * 4);
    float* bufB   = (float*)w;

    const int nbN = (N + 255) / 256;           // 196 for N=50000 (<=256 for scan_top)
    const int nbE = (E + 255) / 256;
    const int nbG = (N + 7) / 8;               // gather: 8 nodes (waves/2) per block
    const int gb  = (N + 63) / 64;             // gemm blocks

    // CSR build (once, reused by both convs)
    cnt_init_k <<<nbN, 256, 0, stream>>>(cnt, N);
    count_k    <<<nbE, 256, 0, stream>>>(ei, cnt, E);
    scan_part_k<<<nbN, 256, 0, stream>>>(cnt, bsum, dinv, N);
    scan_top_k <<<1,   256, 0, stream>>>(bsum, boff, nbN);
    scan_down_k<<<nbN, 256, 0, stream>>>(cnt, boff, rowptr, cursor, N);
    scatter_k  <<<nbE, 256, 0, stream>>>(ei, dinv, cursor, ebuf, E);

    // conv1: gather variant A (prefetch pipeline, under test)
    gemm_k<HID, false><<<gb, 256, 0, stream>>>(x, W1, nullptr, bufA, N);
    gather_pf_k<<<nbG, 256, 0, stream>>>(rowptr, ebuf, dinv, bufA, b1, bufB, N);

    // conv2: gather variant B (R4 control)
    gemm_k<HID, false><<<gb, 256, 0, stream>>>(bufB, W2, nullptr, bufA, N);
    gather_r4_k<<<nbG, 256, 0, stream>>>(rowptr, ebuf, dinv, bufA, b2, bufB, N);

    // head
    gemm_k<OUT_CH, true><<<gb, 256, 0, stream>>>(bufB, Wl, bl, out, N);
    pool_k<<<NGRAPH, 128, 0, stream>>>(batch, bufB, pooled, N);
}